// Round 12
// baseline (154.340 us; speedup 1.0000x reference)
//
#include <hip/hip_runtime.h>
#include <hip/hip_fp16.h>
#include <hip/hip_bf16.h>

#define VINT 50000
#define NN   10000
#define KK   16
#define DINT 8
#define DEXT 16
#define DD   128
#define BB   2048
#define CW   16      // columns per chunk
#define NCH  8       // chunks = XCDs
#define NPB  64      // nodes per gather block

typedef __attribute__((ext_vector_type(8))) short  bf16x8;
typedef __attribute__((ext_vector_type(4))) short  short4v;
typedef __attribute__((ext_vector_type(4))) float  f32x4;

struct __align__(8)  half4 { __half2 a, b; };
struct __align__(16) half8 { __half2 a, b, c, d; };

__device__ inline short bf_rne(float f) {
    unsigned u = __float_as_uint(f);
    return (short)((u + 0x7FFFu + ((u >> 16) & 1u)) >> 16);
}

// packed fp32x8 -> bf16x8 (RNE, identical to bf_rne)
__device__ inline bf16x8 cvt8_bf16(float4 a, float4 b) {
    union { __hip_bfloat162 h2[4]; bf16x8 v; } u;
    u.h2[0] = __float22bfloat162_rn(make_float2(a.x, a.y));
    u.h2[1] = __float22bfloat162_rn(make_float2(a.z, a.w));
    u.h2[2] = __float22bfloat162_rn(make_float2(b.x, b.y));
    u.h2[3] = __float22bfloat162_rn(make_float2(b.z, b.w));
    return u.v;
}

__device__ inline void store_acc(__half* p, f32x4 v) {
    half4 h;
    h.a = __floats2half2_rn(v[0], v[1]);
    h.b = __floats2half2_rn(v[2], v[3]);
    *(half4*)p = h;
}
__device__ inline void store_acc(float* p, f32x4 v) {
    *(float4*)p = make_float4(v[0], v[1], v[2], v[3]);
}

// ---------------------------------------------------------------------------
// fp32 -> bf16 (RNE) bulk convert, float4/thread.  (R8-proven path: the R11
// fused-convert GEMM regressed — scattered fp32 fragment loads.)
// ---------------------------------------------------------------------------
__global__ __launch_bounds__(256) void k_convert(
    const float* __restrict__ src, short* __restrict__ dst, int n4)
{
    int i = blockIdx.x * 256 + threadIdx.x;
    if (i >= n4) return;
    float4 v = ((const float4*)src)[i];
    short4v o = {bf_rne(v.x), bf_rne(v.y), bf_rne(v.z), bf_rne(v.w)};
    ((short4v*)dst)[i] = o;
}

// ---------------------------------------------------------------------------
// Weight mats -> bf16. Blocks [0..15]=W,[16..31]=M,[32..47]=U,[48..63]=V,
// [64..95]=W1 (128x256).
// ---------------------------------------------------------------------------
__global__ __launch_bounds__(256) void k_convert_mats(
    const float* __restrict__ W, const float* __restrict__ M,
    const float* __restrict__ U, const float* __restrict__ V,
    const float* __restrict__ W1,
    short* __restrict__ WMbf, short* __restrict__ UVbf,
    short* __restrict__ W1bf)
{
    int bid = blockIdx.x;
    if (bid < 64) {
        int which = bid >> 4;
        int i = (bid & 15) * 256 + threadIdx.x;
        const float* src = (which == 0) ? W : (which == 1) ? M : (which == 2) ? U : V;
        short* dst = (which < 2) ? WMbf : UVbf;
        int off = (which & 1) * (DD * DD / 4);
        float4 v = ((const float4*)src)[i];
        short4v o = {bf_rne(v.x), bf_rne(v.y), bf_rne(v.z), bf_rne(v.w)};
        ((short4v*)dst)[off + i] = o;
    } else {
        int i = (bid - 64) * 256 + threadIdx.x;
        float4 v = ((const float4*)W1)[i];
        short4v o = {bf_rne(v.x), bf_rne(v.y), bf_rne(v.z), bf_rne(v.w)};
        ((short4v*)W1bf)[i] = o;
    }
}

// ---------------------------------------------------------------------------
// MFMA dual row-transform: OA[v]=A@X[v], OB[v]=B@X[v], bf16 in, fp32 acc.
// CHUNK=true: outputs stored column-chunked OA[(c*VROWS + v)*CW + (m&15)]
// (c = m>>4) for the XCD-local gather; CHUNK=false: row-major [v][DD].
// ---------------------------------------------------------------------------
template <typename OutT, bool CHUNK>
__global__ __launch_bounds__(256, 2) void k_mfma_dual(
    const short* __restrict__ Xbf, const short* __restrict__ ABbf,
    OutT* __restrict__ OA, OutT* __restrict__ OB, int nrows)
{
    const int n0 = blockIdx.x * 64;
    const int w  = threadIdx.x >> 6;
    const int l  = threadIdx.x & 63;
    const int lr = l & 15;
    const int lk = l >> 4;

    f32x4 acc[4][4];
    #pragma unroll
    for (int mi = 0; mi < 4; ++mi)
        #pragma unroll
        for (int ni = 0; ni < 4; ++ni)
            acc[mi][ni] = (f32x4){0.f, 0.f, 0.f, 0.f};

    const bf16x8 zf = {0, 0, 0, 0, 0, 0, 0, 0};

    for (int ks = 0; ks < 4; ++ks) {
        const int kb = ks * 32 + lk * 8;
        bf16x8 ah[4], bh[4];
        #pragma unroll
        for (int mi = 0; mi < 4; ++mi) {
            int m = w * 64 + mi * 16 + lr;
            ah[mi] = *(const bf16x8*)&ABbf[m * DD + kb];
        }
        #pragma unroll
        for (int ni = 0; ni < 4; ++ni) {
            int n = n0 + ni * 16 + lr;
            bh[ni] = (n < nrows) ? *(const bf16x8*)&Xbf[(size_t)n * DD + kb] : zf;
        }
        #pragma unroll
        for (int mi = 0; mi < 4; ++mi)
            #pragma unroll
            for (int ni = 0; ni < 4; ++ni)
                acc[mi][ni] = __builtin_amdgcn_mfma_f32_16x16x32_bf16(ah[mi], bh[ni], acc[mi][ni], 0, 0, 0);
    }

    #pragma unroll
    for (int ni = 0; ni < 4; ++ni) {
        int n = n0 + ni * 16 + lr;
        if (n >= nrows) continue;
        #pragma unroll
        for (int mi = 0; mi < 4; ++mi) {
            int m = w * 64 + mi * 16 + lk * 4;
            OutT* P = (m < DD) ? OA : OB;
            int mm = (m < DD) ? m : m - DD;
            if (CHUNK) {
                size_t off = ((size_t)(mm >> 4) * nrows + n) * CW + (mm & 15);
                store_acc(&P[off], acc[mi][ni]);
            } else {
                store_acc(&P[(size_t)n * DD + mm], acc[mi][ni]);
            }
        }
    }
}

// ---------------------------------------------------------------------------
// Kernel 2a: XCD-chunked gather. Block (c = blockIdx%8, nb = blockIdx/8)
// computes r[n][c*16 .. c*16+16) for 64 nodes: each XCD touches ONLY its
// 3.2 MB chunk of WEc/MEc -> gathers are L2 hits. 4 lanes/node (half4=8B,
// 4 cols each); indices LDS-staged (36 KB). relu is elementwise so the
// column split is exact.
// ---------------------------------------------------------------------------
__global__ __launch_bounds__(256) void k_node_gather(
    const int* __restrict__ node_ids, const int* __restrict__ neigh_ids,
    const __half* __restrict__ WEc, const __half* __restrict__ MEc,
    float* __restrict__ Rbuf)
{
    __shared__ int idxn[NPB][KK];          // 4 KB
    __shared__ int idxg[NPB][KK * DINT];   // 32 KB
    const int c  = blockIdx.x & (NCH - 1);
    const int nb = blockIdx.x >> 3;
    const int t  = threadIdx.x;

    for (int x = t; x < NPB * KK; x += 256) {
        int node = x >> 4, r = x & 15;
        int gn = nb * NPB + node;
        idxn[node][r] = (gn < NN) ? node_ids[gn * KK + r] : 0;
    }
    for (int x = t; x < NPB * KK * DINT; x += 256) {
        int node = x >> 7, r = x & 127;
        int gn = nb * NPB + node;
        idxg[node][r] = (gn < NN) ? neigh_ids[gn * KK * DINT + r] : 0;
    }
    __syncthreads();

    const int nl = t >> 2;        // node local 0..63
    const int q  = t & 3;         // col quad within chunk
    const int n  = nb * NPB + nl;
    const __half* WEb = WEc + (size_t)c * VINT * CW + 4 * q;
    const __half* MEb = MEc + (size_t)c * VINT * CW + 4 * q;

    float r0 = 0.f, r1 = 0.f, r2 = 0.f, r3 = 0.f;
    #pragma unroll 4
    for (int k = 0; k < KK; ++k) {
        half4 wv = *(const half4*)(WEb + (size_t)idxn[nl][k] * CW);
        float2 a0 = __half22float2(wv.a), a1 = __half22float2(wv.b);
        float s0 = a0.x, s1 = a0.y, s2 = a1.x, s3 = a1.y;
        #pragma unroll
        for (int e = 0; e < DINT; ++e) {
            half4 mv = *(const half4*)(MEb + (size_t)idxg[nl][k * DINT + e] * CW);
            float2 b0 = __half22float2(mv.a), b1 = __half22float2(mv.b);
            s0 += b0.x; s1 += b0.y; s2 += b1.x; s3 += b1.y;
        }
        r0 += fmaxf(s0, 0.f); r1 += fmaxf(s1, 0.f);
        r2 += fmaxf(s2, 0.f); r3 += fmaxf(s3, 0.f);
    }
    if (n < NN)
        *(float4*)(Rbuf + (size_t)n * DD + c * CW + 4 * q) = make_float4(r0, r1, r2, r3);
}

// ---------------------------------------------------------------------------
// Kernel 2b: row softmax over Rbuf -> Hbf (bf16). One node per wave
// (both 32-halves duplicate the work; half 0 writes).
// ---------------------------------------------------------------------------
__global__ __launch_bounds__(256) void k_node_softmax(
    const float* __restrict__ Rbuf, short* __restrict__ Hbf)
{
    const int t = threadIdx.x;
    const int w = t >> 6, l = t & 63;
    const int cc = l & 31;
    const int n = blockIdx.x * 4 + w;
    float4 v = *(const float4*)(Rbuf + (size_t)n * DD + 4 * cc);
    float mx = fmaxf(fmaxf(v.x, v.y), fmaxf(v.z, v.w));
    #pragma unroll
    for (int off = 16; off >= 1; off >>= 1) mx = fmaxf(mx, __shfl_xor(mx, off));
    float e0 = expf(v.x - mx), e1 = expf(v.y - mx), e2 = expf(v.z - mx), e3 = expf(v.w - mx);
    float s = e0 + e1 + e2 + e3;
    #pragma unroll
    for (int off = 16; off >= 1; off >>= 1) s += __shfl_xor(s, off);
    float inv = 1.f / s;
    if (l < 32) {
        short4v o = {bf_rne(e0 * inv), bf_rne(e1 * inv), bf_rne(e2 * inv), bf_rne(e3 * inv)};
        *(short4v*)(Hbf + (size_t)n * DD + 4 * cc) = o;
    }
}

// ---------------------------------------------------------------------------
// Kernel 3: e_all[n] = softmax(relu(UH[n] + sum_j VH[ext[n,j]])), fp16 tables.
// ---------------------------------------------------------------------------
__global__ __launch_bounds__(256) void k_ext2(
    const int* __restrict__ ext_neigh, const __half* __restrict__ UH,
    const __half* __restrict__ VH, float* __restrict__ EALL)
{
    __shared__ int idx[4][DEXT];
    const int t  = threadIdx.x;
    const int n0 = blockIdx.x * 4;
    if (t < 4 * DEXT) idx[t >> 4][t & 15] = ext_neigh[n0 * DEXT + t];
    __syncthreads();

    const int w  = t >> 6;
    const int l  = t & 63;
    const int c  = l & 31;
    const int hf = l >> 5;
    const int n  = n0 + w;

    float sx = 0.f, sy = 0.f, sz = 0.f, sw = 0.f;
    if (hf == 0) {
        half4 a = *(const half4*)(UH + (size_t)n * DD + 4 * c);
        float2 a0 = __half22float2(a.a), a1 = __half22float2(a.b);
        sx = a0.x; sy = a0.y; sz = a1.x; sw = a1.y;
    }
    #pragma unroll
    for (int jj = 0; jj < 8; ++jj) {
        half4 v = *(const half4*)(VH + (size_t)idx[w][hf * 8 + jj] * DD + 4 * c);
        float2 v0 = __half22float2(v.a), v1 = __half22float2(v.b);
        sx += v0.x; sy += v0.y; sz += v1.x; sw += v1.y;
    }
    sx += __shfl_xor(sx, 32); sy += __shfl_xor(sy, 32);
    sz += __shfl_xor(sz, 32); sw += __shfl_xor(sw, 32);

    sx = fmaxf(sx, 0.f); sy = fmaxf(sy, 0.f);
    sz = fmaxf(sz, 0.f); sw = fmaxf(sw, 0.f);

    float mx = fmaxf(fmaxf(sx, sy), fmaxf(sz, sw));
    #pragma unroll
    for (int off = 16; off >= 1; off >>= 1) mx = fmaxf(mx, __shfl_xor(mx, off));
    float ex = expf(sx - mx), ey = expf(sy - mx), ez = expf(sz - mx), ew = expf(sw - mx);
    float s = ex + ey + ez + ew;
    #pragma unroll
    for (int off = 16; off >= 1; off >>= 1) s += __shfl_xor(s, off);
    float inv = 1.f / s;
    if (hf == 0)
        *(float4*)(EALL + (size_t)n * DD + 4 * c) = make_float4(ex * inv, ey * inv, ez * inv, ew * inv);
}

// ---------------------------------------------------------------------------
// Kernel 4 (MFMA): 64 batch pairs per block; softmax-2 epilogue.
// ---------------------------------------------------------------------------
__global__ __launch_bounds__(256) void k_mlp_mfma(
    const int* __restrict__ batch, const float* __restrict__ EA,
    const short* __restrict__ W1bf, const float* __restrict__ b1,
    const float* __restrict__ W2, const float* __restrict__ b2,
    float* __restrict__ out)
{
    __shared__ int pidx[128];
    __shared__ float red0[4][64];
    __shared__ float red1[4][64];
    const int t = threadIdx.x, w = t >> 6, l = t & 63;
    const int lr = l & 15, lk = l >> 4;
    const int b0 = blockIdx.x * 64;

    if (t < 128) pidx[t] = batch[b0 * 2 + t];
    __syncthreads();

    f32x4 acc[2][4];
    #pragma unroll
    for (int mi = 0; mi < 2; ++mi)
        #pragma unroll
        for (int ni = 0; ni < 4; ++ni)
            acc[mi][ni] = (f32x4){0.f, 0.f, 0.f, 0.f};

    for (int ks = 0; ks < 8; ++ks) {
        const int kb = ks * 32 + lk * 8;
        const int sel = (ks >= 4);
        const int koff = kb - sel * 128;
        bf16x8 ah[2], bh[4];
        #pragma unroll
        for (int mi = 0; mi < 2; ++mi) {
            int m = w * 32 + mi * 16 + lr;
            ah[mi] = *(const bf16x8*)&W1bf[m * (2 * DD) + kb];
        }
        #pragma unroll
        for (int ni = 0; ni < 4; ++ni) {
            int n = ni * 16 + lr;
            int row = pidx[2 * n + sel];
            float4 v0 = *(const float4*)&EA[(size_t)row * DD + koff];
            float4 v1 = *(const float4*)&EA[(size_t)row * DD + koff + 4];
            bh[ni] = cvt8_bf16(v0, v1);
        }
        #pragma unroll
        for (int mi = 0; mi < 2; ++mi)
            #pragma unroll
            for (int ni = 0; ni < 4; ++ni)
                acc[mi][ni] = __builtin_amdgcn_mfma_f32_16x16x32_bf16(ah[mi], bh[ni], acc[mi][ni], 0, 0, 0);
    }

    float bb[2][4], w2a[2][4], w2b[2][4];
    #pragma unroll
    for (int mi = 0; mi < 2; ++mi)
        #pragma unroll
        for (int rr = 0; rr < 4; ++rr) {
            int m = w * 32 + mi * 16 + lk * 4 + rr;
            bb[mi][rr]  = b1[m];
            w2a[mi][rr] = W2[m];
            w2b[mi][rr] = W2[DD + m];
        }

    #pragma unroll
    for (int ni = 0; ni < 4; ++ni) {
        float p0 = 0.f, p1 = 0.f;
        #pragma unroll
        for (int mi = 0; mi < 2; ++mi)
            #pragma unroll
            for (int rr = 0; rr < 4; ++rr) {
                float x = acc[mi][ni][rr] + bb[mi][rr];
                x = (x > 0.f) ? x : 0.01f * x;
                p0 = fmaf(w2a[mi][rr], x, p0);
                p1 = fmaf(w2b[mi][rr], x, p1);
            }
        p0 += __shfl_xor(p0, 16); p0 += __shfl_xor(p0, 32);
        p1 += __shfl_xor(p1, 16); p1 += __shfl_xor(p1, 32);
        if (lk == 0) {
            red0[w][ni * 16 + lr] = p0;
            red1[w][ni * 16 + lr] = p1;
        }
    }
    __syncthreads();
    if (t < 64) {
        float l0 = red0[0][t] + red0[1][t] + red0[2][t] + red0[3][t] + b2[0];
        float l1 = red1[0][t] + red1[1][t] + red1[2][t] + red1[3][t] + b2[1];
        float mm = fmaxf(l0, l1);
        float e0 = expf(l0 - mm), e1 = expf(l1 - mm);
        float inv = 1.f / (e0 + e1);
        out[2 * (b0 + t)]     = e0 * inv;
        out[2 * (b0 + t) + 1] = e1 * inv;
    }
}

// ---------------------------------------------------------------------------
extern "C" void kernel_launch(void* const* d_in, const int* in_sizes, int n_in,
                              void* d_out, int out_size, void* d_ws, size_t ws_size,
                              hipStream_t stream) {
    const int*   batch     = (const int*)d_in[0];
    const int*   node_ids  = (const int*)d_in[1];
    const int*   neigh_ids = (const int*)d_in[2];
    const int*   ext_neigh = (const int*)d_in[3];
    const float* E         = (const float*)d_in[4];
    const float* W         = (const float*)d_in[5];
    const float* M         = (const float*)d_in[6];
    const float* U         = (const float*)d_in[7];
    const float* V         = (const float*)d_in[8];
    const float* W1        = (const float*)d_in[9];
    const float* b1        = (const float*)d_in[10];
    const float* W2        = (const float*)d_in[11];
    const float* b2        = (const float*)d_in[12];

    // workspace layout (~56.7 MB, all 16B-aligned)
    __half* WEc  = (__half*)d_ws;                    // 12.8 MB (chunked)
    __half* MEc  = WEc + (size_t)VINT * DD;          // 12.8 MB (chunked)
    short*  Ebf  = (short*)(MEc + (size_t)VINT * DD);// 12.8 MB
    float*  Rbuf = (float*)(Ebf + (size_t)VINT * DD);// 5.12 MB
    short*  Hbf  = (short*)(Rbuf + (size_t)NN * DD); // 2.56 MB
    short*  WMbf = Hbf + (size_t)NN * DD;            // 64 KB
    short*  UVbf = WMbf + 256 * DD;                  // 64 KB
    short*  W1bf = UVbf + 256 * DD;                  // 64 KB
    __half* UHh  = (__half*)(W1bf + DD * 2 * DD);    // 2.56 MB
    __half* VHh  = UHh + (size_t)NN * DD;            // 2.56 MB
    float*  EA   = (float*)(VHh + (size_t)NN * DD);  // 5.12 MB
    float*  out  = (float*)d_out;

    const int NB = (NN + NPB - 1) / NPB;   // 157

    k_convert<<<(VINT * DD / 4 + 255) / 256, 256, 0, stream>>>(E, Ebf, VINT * DD / 4);
    k_convert_mats<<<96, 256, 0, stream>>>(W, M, U, V, W1, WMbf, UVbf, W1bf);
    k_mfma_dual<__half, true><<<(VINT + 63) / 64, 256, 0, stream>>>(Ebf, WMbf, WEc, MEc, VINT);
    k_node_gather<<<NCH * NB, 256, 0, stream>>>(node_ids, neigh_ids, WEc, MEc, Rbuf);
    k_node_softmax<<<NN / 4, 256, 0, stream>>>(Rbuf, Hbf);
    k_mfma_dual<__half, false><<<(NN + 63) / 64, 256, 0, stream>>>(Hbf, UVbf, UHh, VHh, NN);
    k_ext2<<<NN / 4, 256, 0, stream>>>(ext_neigh, UHh, VHh, EA);
    k_mlp_mfma<<<BB / 64, 256, 0, stream>>>(batch, EA, W1bf, b1, W2, b2, out);
}

// Round 13
// 100.416 us; speedup vs baseline: 1.5370x; 1.5370x over previous
//
#include <hip/hip_runtime.h>
#include <hip/hip_fp16.h>
#include <hip/hip_bf16.h>

#define VINT 50000
#define NN   10000
#define KK   16
#define DINT 8
#define DEXT 16
#define DD   128
#define BB   2048

typedef __attribute__((ext_vector_type(8))) short  bf16x8;
typedef __attribute__((ext_vector_type(4))) short  short4v;
typedef __attribute__((ext_vector_type(4))) float  f32x4;

struct __align__(8)  half4 { __half2 a, b; };
struct __align__(16) half8 { __half2 a, b, c, d; };

__device__ inline short bf_rne(float f) {
    unsigned u = __float_as_uint(f);
    return (short)((u + 0x7FFFu + ((u >> 16) & 1u)) >> 16);
}

__device__ inline void store_acc(__half* p, f32x4 v) {
    half4 h;
    h.a = __floats2half2_rn(v[0], v[1]);
    h.b = __floats2half2_rn(v[2], v[3]);
    *(half4*)p = h;
}
__device__ inline void store_acc(float* p, f32x4 v) {
    *(float4*)p = make_float4(v[0], v[1], v[2], v[3]);
}

// ---------------------------------------------------------------------------
// Weight mats -> bf16. Blocks [0..15]=W,[16..31]=M,[32..47]=U,[48..63]=V,
// [64..95]=W1 (128x256). W/M stack into WMbf rows 0-255; U/V into UVbf.
// ---------------------------------------------------------------------------
__global__ __launch_bounds__(256) void k_convert_mats(
    const float* __restrict__ W, const float* __restrict__ M,
    const float* __restrict__ U, const float* __restrict__ V,
    const float* __restrict__ W1,
    short* __restrict__ WMbf, short* __restrict__ UVbf,
    short* __restrict__ W1bf)
{
    int bid = blockIdx.x;
    if (bid < 64) {
        int which = bid >> 4;
        int i = (bid & 15) * 256 + threadIdx.x;
        const float* src = (which == 0) ? W : (which == 1) ? M : (which == 2) ? U : V;
        short* dst = (which < 2) ? WMbf : UVbf;
        int off = (which & 1) * (DD * DD / 4);
        float4 v = ((const float4*)src)[i];
        short4v o = {bf_rne(v.x), bf_rne(v.y), bf_rne(v.z), bf_rne(v.w)};
        ((short4v*)dst)[off + i] = o;
    } else {
        int i = (bid - 64) * 256 + threadIdx.x;
        float4 v = ((const float4*)W1)[i];
        short4v o = {bf_rne(v.x), bf_rne(v.y), bf_rne(v.z), bf_rne(v.w)};
        ((short4v*)W1bf)[i] = o;
    }
}

// ---------------------------------------------------------------------------
// MFMA dual row-transform with FUSED fp32->bf16 convert via LDS staging:
// OA[v] = A @ X[v], OB[v] = B @ X[v]. The fp32 X-tile (64 rows x 128) is
// read with perfectly-coalesced float4 streaming loads, packed-cvt'd to
// bf16 into a padded LDS tile (64 x 136 shorts: 2-way max bank aliasing),
// and fragments come from ds_read_b128. This fixes both prior fusion
// failures (R7: scalar cvt chains; R11: scattered fp32 fragment loads)
// and deletes the 51.2 MB Ebf round-trip + one launch.
// ---------------------------------------------------------------------------
template <typename OutT>
__global__ __launch_bounds__(256, 2) void k_mfma_dual_f32lds(
    const float* __restrict__ X, const short* __restrict__ ABbf,
    OutT* __restrict__ OA, OutT* __restrict__ OB, int nrows)
{
    __shared__ short Bs[64][136];     // 17.4 KB, rows 16B-aligned (272 B)
    const int n0 = blockIdx.x * 64;
    const int t  = threadIdx.x;
    const int w  = t >> 6;
    const int l  = t & 63;
    const int lr = l & 15;
    const int lk = l >> 4;

    // stage + convert: 64 rows x 32 float4 = 2048 float4, 8 per thread
    #pragma unroll
    for (int i = 0; i < 8; ++i) {
        int f   = i * 256 + t;
        int row = f >> 5, c4 = f & 31;
        int vv  = n0 + row;
        float4 v = (vv < nrows) ? *(const float4*)&X[(size_t)vv * DD + c4 * 4]
                                : make_float4(0.f, 0.f, 0.f, 0.f);
        union { __hip_bfloat162 h2[2]; short4v s; } u;
        u.h2[0] = __float22bfloat162_rn(make_float2(v.x, v.y));
        u.h2[1] = __float22bfloat162_rn(make_float2(v.z, v.w));
        *(short4v*)&Bs[row][c4 * 4] = u.s;
    }
    __syncthreads();

    f32x4 acc[4][4];
    #pragma unroll
    for (int mi = 0; mi < 4; ++mi)
        #pragma unroll
        for (int ni = 0; ni < 4; ++ni)
            acc[mi][ni] = (f32x4){0.f, 0.f, 0.f, 0.f};

    for (int ks = 0; ks < 4; ++ks) {
        const int kb = ks * 32 + lk * 8;
        bf16x8 ah[4], bh[4];
        #pragma unroll
        for (int mi = 0; mi < 4; ++mi) {
            int m = w * 64 + mi * 16 + lr;
            ah[mi] = *(const bf16x8*)&ABbf[m * DD + kb];
        }
        #pragma unroll
        for (int ni = 0; ni < 4; ++ni)
            bh[ni] = *(const bf16x8*)&Bs[ni * 16 + lr][kb];
        #pragma unroll
        for (int mi = 0; mi < 4; ++mi)
            #pragma unroll
            for (int ni = 0; ni < 4; ++ni)
                acc[mi][ni] = __builtin_amdgcn_mfma_f32_16x16x32_bf16(ah[mi], bh[ni], acc[mi][ni], 0, 0, 0);
    }

    // D[m][n]: lane holds col n=tile+lr, rows m=tile+lk*4+r (r=0..3).
    #pragma unroll
    for (int ni = 0; ni < 4; ++ni) {
        int n = n0 + ni * 16 + lr;
        if (n >= nrows) continue;
        #pragma unroll
        for (int mi = 0; mi < 4; ++mi) {
            int m = w * 64 + mi * 16 + lk * 4;
            if (m < DD) store_acc(&OA[(size_t)n * DD + m], acc[mi][ni]);
            else        store_acc(&OB[(size_t)n * DD + (m - DD)], acc[mi][ni]);
        }
    }
}

// ---------------------------------------------------------------------------
// MFMA dual row-transform, bf16 input (for Hbf -> UH/VH).
// ---------------------------------------------------------------------------
template <typename OutT>
__global__ __launch_bounds__(256, 2) void k_mfma_dual(
    const short* __restrict__ Xbf, const short* __restrict__ ABbf,
    OutT* __restrict__ OA, OutT* __restrict__ OB, int nrows)
{
    const int n0 = blockIdx.x * 64;
    const int w  = threadIdx.x >> 6;
    const int l  = threadIdx.x & 63;
    const int lr = l & 15;
    const int lk = l >> 4;

    f32x4 acc[4][4];
    #pragma unroll
    for (int mi = 0; mi < 4; ++mi)
        #pragma unroll
        for (int ni = 0; ni < 4; ++ni)
            acc[mi][ni] = (f32x4){0.f, 0.f, 0.f, 0.f};

    const bf16x8 zf = {0, 0, 0, 0, 0, 0, 0, 0};

    for (int ks = 0; ks < 4; ++ks) {
        const int kb = ks * 32 + lk * 8;
        bf16x8 ah[4], bh[4];
        #pragma unroll
        for (int mi = 0; mi < 4; ++mi) {
            int m = w * 64 + mi * 16 + lr;
            ah[mi] = *(const bf16x8*)&ABbf[m * DD + kb];
        }
        #pragma unroll
        for (int ni = 0; ni < 4; ++ni) {
            int n = n0 + ni * 16 + lr;
            bh[ni] = (n < nrows) ? *(const bf16x8*)&Xbf[(size_t)n * DD + kb] : zf;
        }
        #pragma unroll
        for (int mi = 0; mi < 4; ++mi)
            #pragma unroll
            for (int ni = 0; ni < 4; ++ni)
                acc[mi][ni] = __builtin_amdgcn_mfma_f32_16x16x32_bf16(ah[mi], bh[ni], acc[mi][ni], 0, 0, 0);
    }

    #pragma unroll
    for (int ni = 0; ni < 4; ++ni) {
        int n = n0 + ni * 16 + lr;
        if (n >= nrows) continue;
        #pragma unroll
        for (int mi = 0; mi < 4; ++mi) {
            int m = w * 64 + mi * 16 + lk * 4;
            if (m < DD) store_acc(&OA[(size_t)n * DD + m], acc[mi][ni]);
            else        store_acc(&OB[(size_t)n * DD + (m - DD)], acc[mi][ni]);
        }
    }
}

// ---------------------------------------------------------------------------
// Kernel 2: per node n: r[d] = sum_k relu(WE[nid]+sum_e ME[gid]); h=softmax(r).
// R8 PINNED version (43.9 us, FETCH 139 MB, miss-path BW ceiling): one node
// per wave-64, 4 k-streams x 16 lanes x 16B loads, batch-issued rows.
// Six variants (R6-R12: load width, reg batching, dbuf, 2x/4x wave count,
// XCD chunking) were all flat or worse — do not touch.
// ---------------------------------------------------------------------------
__global__ __launch_bounds__(256, 7) void k_node(
    const int* __restrict__ node_ids, const int* __restrict__ neigh_ids,
    const __half* __restrict__ WE, const __half* __restrict__ ME,
    short* __restrict__ Hbf)
{
    __shared__ int idx[4][KK * (1 + DINT)];   // per node: [0..15]=nid, [16..143]=gid
    const int t  = threadIdx.x;
    const int n0 = blockIdx.x * 4;

    if (t < 4 * KK) idx[t >> 4][t & 15] = node_ids[n0 * KK + t];
    for (int x = t; x < 4 * KK * DINT; x += 256)
        idx[x >> 7][KK + (x & 127)] = neigh_ids[n0 * KK * DINT + x];
    __syncthreads();

    const int w   = t >> 6;         // node within block
    const int l   = t & 63;
    const int g16 = l >> 4;         // k-stream 0..3
    const int p   = l & 15;         // 16B-chunk position in row
    const int n   = n0 + w;
    const int* ids = idx[w];

    float r[8] = {0.f, 0.f, 0.f, 0.f, 0.f, 0.f, 0.f, 0.f};
    #pragma unroll
    for (int kk = 0; kk < 4; ++kk) {
        const int k = kk * 4 + g16;
        half8 rw = *(const half8*)(WE + (size_t)ids[k] * DD + p * 8);
        half8 rm[DINT];
        #pragma unroll
        for (int e = 0; e < DINT; ++e)
            rm[e] = *(const half8*)(ME + (size_t)ids[KK + k * DINT + e] * DD + p * 8);

        float2 f0 = __half22float2(rw.a), f1 = __half22float2(rw.b);
        float2 f2 = __half22float2(rw.c), f3 = __half22float2(rw.d);
        float s[8] = {f0.x, f0.y, f1.x, f1.y, f2.x, f2.y, f3.x, f3.y};
        #pragma unroll
        for (int e = 0; e < DINT; ++e) {
            float2 m0 = __half22float2(rm[e].a), m1 = __half22float2(rm[e].b);
            float2 m2 = __half22float2(rm[e].c), m3 = __half22float2(rm[e].d);
            s[0] += m0.x; s[1] += m0.y; s[2] += m1.x; s[3] += m1.y;
            s[4] += m2.x; s[5] += m2.y; s[6] += m3.x; s[7] += m3.y;
        }
        #pragma unroll
        for (int j = 0; j < 8; ++j) r[j] += fmaxf(s[j], 0.f);
    }

    #pragma unroll
    for (int j = 0; j < 8; ++j) {
        r[j] += __shfl_xor(r[j], 16);
        r[j] += __shfl_xor(r[j], 32);
    }

    float mx = r[0];
    #pragma unroll
    for (int j = 1; j < 8; ++j) mx = fmaxf(mx, r[j]);
    #pragma unroll
    for (int off = 8; off >= 1; off >>= 1) mx = fmaxf(mx, __shfl_xor(mx, off));
    float e[8], sum = 0.f;
    #pragma unroll
    for (int j = 0; j < 8; ++j) { e[j] = expf(r[j] - mx); sum += e[j]; }
    #pragma unroll
    for (int off = 8; off >= 1; off >>= 1) sum += __shfl_xor(sum, off);
    float inv = 1.f / sum;
    if (g16 == 0) {
        bf16x8 o = {bf_rne(e[0] * inv), bf_rne(e[1] * inv), bf_rne(e[2] * inv), bf_rne(e[3] * inv),
                    bf_rne(e[4] * inv), bf_rne(e[5] * inv), bf_rne(e[6] * inv), bf_rne(e[7] * inv)};
        *(bf16x8*)(Hbf + (size_t)n * DD + p * 8) = o;
    }
}

// ---------------------------------------------------------------------------
// Kernel 3: e_all[n] = softmax(relu(UH[n] + sum_j VH[ext[n,j]])), fp16 tables.
// ---------------------------------------------------------------------------
__global__ __launch_bounds__(256) void k_ext2(
    const int* __restrict__ ext_neigh, const __half* __restrict__ UH,
    const __half* __restrict__ VH, float* __restrict__ EALL)
{
    __shared__ int idx[4][DEXT];
    const int t  = threadIdx.x;
    const int n0 = blockIdx.x * 4;
    if (t < 4 * DEXT) idx[t >> 4][t & 15] = ext_neigh[n0 * DEXT + t];
    __syncthreads();

    const int w  = t >> 6;
    const int l  = t & 63;
    const int c  = l & 31;
    const int hf = l >> 5;
    const int n  = n0 + w;

    float sx = 0.f, sy = 0.f, sz = 0.f, sw = 0.f;
    if (hf == 0) {
        half4 a = *(const half4*)(UH + (size_t)n * DD + 4 * c);
        float2 a0 = __half22float2(a.a), a1 = __half22float2(a.b);
        sx = a0.x; sy = a0.y; sz = a1.x; sw = a1.y;
    }
    #pragma unroll
    for (int jj = 0; jj < 8; ++jj) {
        half4 v = *(const half4*)(VH + (size_t)idx[w][hf * 8 + jj] * DD + 4 * c);
        float2 v0 = __half22float2(v.a), v1 = __half22float2(v.b);
        sx += v0.x; sy += v0.y; sz += v1.x; sw += v1.y;
    }
    sx += __shfl_xor(sx, 32); sy += __shfl_xor(sy, 32);
    sz += __shfl_xor(sz, 32); sw += __shfl_xor(sw, 32);

    sx = fmaxf(sx, 0.f); sy = fmaxf(sy, 0.f);
    sz = fmaxf(sz, 0.f); sw = fmaxf(sw, 0.f);

    float mx = fmaxf(fmaxf(sx, sy), fmaxf(sz, sw));
    #pragma unroll
    for (int off = 16; off >= 1; off >>= 1) mx = fmaxf(mx, __shfl_xor(mx, off));
    float ex = expf(sx - mx), ey = expf(sy - mx), ez = expf(sz - mx), ew = expf(sw - mx);
    float s = ex + ey + ez + ew;
    #pragma unroll
    for (int off = 16; off >= 1; off >>= 1) s += __shfl_xor(s, off);
    float inv = 1.f / s;
    if (hf == 0)
        *(float4*)(EALL + (size_t)n * DD + 4 * c) = make_float4(ex * inv, ey * inv, ez * inv, ew * inv);
}

// ---------------------------------------------------------------------------
// Kernel 4 (MFMA): 64 batch pairs per block. X = leaky(W1 @ cat^T + b1);
// logits = W2 @ X + b2; softmax-2.
// ---------------------------------------------------------------------------
__global__ __launch_bounds__(256) void k_mlp_mfma(
    const int* __restrict__ batch, const float* __restrict__ EA,
    const short* __restrict__ W1bf, const float* __restrict__ b1,
    const float* __restrict__ W2, const float* __restrict__ b2,
    float* __restrict__ out)
{
    __shared__ int pidx[128];
    __shared__ float red0[4][64];
    __shared__ float red1[4][64];
    const int t = threadIdx.x, w = t >> 6, l = t & 63;
    const int lr = l & 15, lk = l >> 4;
    const int b0 = blockIdx.x * 64;

    if (t < 128) pidx[t] = batch[b0 * 2 + t];
    __syncthreads();

    f32x4 acc[2][4];
    #pragma unroll
    for (int mi = 0; mi < 2; ++mi)
        #pragma unroll
        for (int ni = 0; ni < 4; ++ni)
            acc[mi][ni] = (f32x4){0.f, 0.f, 0.f, 0.f};

    for (int ks = 0; ks < 8; ++ks) {
        const int kb = ks * 32 + lk * 8;
        const int sel = (ks >= 4);
        const int koff = kb - sel * 128;
        bf16x8 ah[2], bh[4];
        #pragma unroll
        for (int mi = 0; mi < 2; ++mi) {
            int m = w * 32 + mi * 16 + lr;
            ah[mi] = *(const bf16x8*)&W1bf[m * (2 * DD) + kb];
        }
        #pragma unroll
        for (int ni = 0; ni < 4; ++ni) {
            int n = ni * 16 + lr;
            int row = pidx[2 * n + sel];
            float4 v0 = *(const float4*)&EA[(size_t)row * DD + koff];
            float4 v1 = *(const float4*)&EA[(size_t)row * DD + koff + 4];
            union { __hip_bfloat162 h2[4]; bf16x8 v; } u;
            u.h2[0] = __float22bfloat162_rn(make_float2(v0.x, v0.y));
            u.h2[1] = __float22bfloat162_rn(make_float2(v0.z, v0.w));
            u.h2[2] = __float22bfloat162_rn(make_float2(v1.x, v1.y));
            u.h2[3] = __float22bfloat162_rn(make_float2(v1.z, v1.w));
            bh[ni] = u.v;
        }
        #pragma unroll
        for (int mi = 0; mi < 2; ++mi)
            #pragma unroll
            for (int ni = 0; ni < 4; ++ni)
                acc[mi][ni] = __builtin_amdgcn_mfma_f32_16x16x32_bf16(ah[mi], bh[ni], acc[mi][ni], 0, 0, 0);
    }

    float bb[2][4], w2a[2][4], w2b[2][4];
    #pragma unroll
    for (int mi = 0; mi < 2; ++mi)
        #pragma unroll
        for (int rr = 0; rr < 4; ++rr) {
            int m = w * 32 + mi * 16 + lk * 4 + rr;
            bb[mi][rr]  = b1[m];
            w2a[mi][rr] = W2[m];
            w2b[mi][rr] = W2[DD + m];
        }

    #pragma unroll
    for (int ni = 0; ni < 4; ++ni) {
        float p0 = 0.f, p1 = 0.f;
        #pragma unroll
        for (int mi = 0; mi < 2; ++mi)
            #pragma unroll
            for (int rr = 0; rr < 4; ++rr) {
                float x = acc[mi][ni][rr] + bb[mi][rr];
                x = (x > 0.f) ? x : 0.01f * x;
                p0 = fmaf(w2a[mi][rr], x, p0);
                p1 = fmaf(w2b[mi][rr], x, p1);
            }
        p0 += __shfl_xor(p0, 16); p0 += __shfl_xor(p0, 32);
        p1 += __shfl_xor(p1, 16); p1 += __shfl_xor(p1, 32);
        if (lk == 0) {
            red0[w][ni * 16 + lr] = p0;
            red1[w][ni * 16 + lr] = p1;
        }
    }
    __syncthreads();
    if (t < 64) {
        float l0 = red0[0][t] + red0[1][t] + red0[2][t] + red0[3][t] + b2[0];
        float l1 = red1[0][t] + red1[1][t] + red1[2][t] + red1[3][t] + b2[1];
        float mm = fmaxf(l0, l1);
        float e0 = expf(l0 - mm), e1 = expf(l1 - mm);
        float inv = 1.f / (e0 + e1);
        out[2 * (b0 + t)]     = e0 * inv;
        out[2 * (b0 + t) + 1] = e1 * inv;
    }
}

// ---------------------------------------------------------------------------
extern "C" void kernel_launch(void* const* d_in, const int* in_sizes, int n_in,
                              void* d_out, int out_size, void* d_ws, size_t ws_size,
                              hipStream_t stream) {
    const int*   batch     = (const int*)d_in[0];
    const int*   node_ids  = (const int*)d_in[1];
    const int*   neigh_ids = (const int*)d_in[2];
    const int*   ext_neigh = (const int*)d_in[3];
    const float* E         = (const float*)d_in[4];
    const float* W         = (const float*)d_in[5];
    const float* M         = (const float*)d_in[6];
    const float* U         = (const float*)d_in[7];
    const float* V         = (const float*)d_in[8];
    const float* W1        = (const float*)d_in[9];
    const float* b1        = (const float*)d_in[10];
    const float* W2        = (const float*)d_in[11];
    const float* b2        = (const float*)d_in[12];

    // workspace layout (~39 MB, all 16B-aligned)
    __half* WE   = (__half*)d_ws;                    // 12.8 MB
    __half* ME   = WE + (size_t)VINT * DD;           // 12.8 MB
    short*  Hbf  = (short*)(ME + (size_t)VINT * DD); // 2.56 MB
    short*  WMbf = Hbf + (size_t)NN * DD;            // 64 KB
    short*  UVbf = WMbf + 256 * DD;                  // 64 KB
    short*  W1bf = UVbf + 256 * DD;                  // 64 KB
    __half* UHh  = (__half*)(W1bf + DD * 2 * DD);    // 2.56 MB
    __half* VHh  = UHh + (size_t)NN * DD;            // 2.56 MB
    float*  EA   = (float*)(VHh + (size_t)NN * DD);  // 5.12 MB
    float*  out  = (float*)d_out;

    k_convert_mats<<<96, 256, 0, stream>>>(W, M, U, V, W1, WMbf, UVbf, W1bf);
    k_mfma_dual_f32lds<__half><<<(VINT + 63) / 64, 256, 0, stream>>>(E, WMbf, WE, ME, VINT);
    k_node<<<NN / 4, 256, 0, stream>>>(node_ids, neigh_ids, WE, ME, Hbf);
    k_mfma_dual<__half><<<(NN + 63) / 64, 256, 0, stream>>>(Hbf, UVbf, UHh, VHh, NN);
    k_ext2<<<NN / 4, 256, 0, stream>>>(ext_neigh, UHh, VHh, EA);
    k_mlp_mfma<<<BB / 64, 256, 0, stream>>>(batch, EA, W1bf, b1, W2, b2, out);
}

// Round 14
// 95.038 us; speedup vs baseline: 1.6240x; 1.0566x over previous
//
#include <hip/hip_runtime.h>
#include <hip/hip_fp16.h>
#include <hip/hip_bf16.h>

#define VINT 50000
#define NN   10000
#define KK   16
#define DINT 8
#define DEXT 16
#define DD   128
#define BB   2048

typedef __attribute__((ext_vector_type(8))) short  bf16x8;
typedef __attribute__((ext_vector_type(4))) short  short4v;
typedef __attribute__((ext_vector_type(4))) float  f32x4;

struct __align__(8)  half4 { __half2 a, b; };
struct __align__(16) half8 { __half2 a, b, c, d; };

__device__ inline short bf_rne(float f) {
    unsigned u = __float_as_uint(f);
    return (short)((u + 0x7FFFu + ((u >> 16) & 1u)) >> 16);
}

__device__ inline void store_acc(__half* p, f32x4 v) {
    half4 h;
    h.a = __floats2half2_rn(v[0], v[1]);
    h.b = __floats2half2_rn(v[2], v[3]);
    *(half4*)p = h;
}
__device__ inline void store_acc(float* p, f32x4 v) {
    *(float4*)p = make_float4(v[0], v[1], v[2], v[3]);
}

// ---------------------------------------------------------------------------
// Weight mats -> bf16. Blocks [0..15]=W,[16..31]=M,[32..47]=U,[48..63]=V,
// [64..95]=W1 (128x256). W/M stack into WMbf rows 0-255; U/V into UVbf.
// ---------------------------------------------------------------------------
__global__ __launch_bounds__(256) void k_convert_mats(
    const float* __restrict__ W, const float* __restrict__ M,
    const float* __restrict__ U, const float* __restrict__ V,
    const float* __restrict__ W1,
    short* __restrict__ WMbf, short* __restrict__ UVbf,
    short* __restrict__ W1bf)
{
    int bid = blockIdx.x;
    if (bid < 64) {
        int which = bid >> 4;
        int i = (bid & 15) * 256 + threadIdx.x;
        const float* src = (which == 0) ? W : (which == 1) ? M : (which == 2) ? U : V;
        short* dst = (which < 2) ? WMbf : UVbf;
        int off = (which & 1) * (DD * DD / 4);
        float4 v = ((const float4*)src)[i];
        short4v o = {bf_rne(v.x), bf_rne(v.y), bf_rne(v.z), bf_rne(v.w)};
        ((short4v*)dst)[off + i] = o;
    } else {
        int i = (bid - 64) * 256 + threadIdx.x;
        float4 v = ((const float4*)W1)[i];
        short4v o = {bf_rne(v.x), bf_rne(v.y), bf_rne(v.z), bf_rne(v.w)};
        ((short4v*)W1bf)[i] = o;
    }
}

// ---------------------------------------------------------------------------
// MFMA dual row-transform with fused fp32->bf16 convert via LDS staging
// (R13-proven: coalesced float4 reads -> packed cvt -> padded LDS tile ->
// ds_read_b128 fragments). OA[v] = A @ X[v], OB[v] = B @ X[v].
// ---------------------------------------------------------------------------
template <typename OutT>
__global__ __launch_bounds__(256, 2) void k_mfma_dual_f32lds(
    const float* __restrict__ X, const short* __restrict__ ABbf,
    OutT* __restrict__ OA, OutT* __restrict__ OB, int nrows)
{
    __shared__ short Bs[64][136];     // 17.4 KB, rows 16B-aligned
    const int n0 = blockIdx.x * 64;
    const int t  = threadIdx.x;
    const int w  = t >> 6;
    const int l  = t & 63;
    const int lr = l & 15;
    const int lk = l >> 4;

    #pragma unroll
    for (int i = 0; i < 8; ++i) {
        int f   = i * 256 + t;
        int row = f >> 5, c4 = f & 31;
        int vv  = n0 + row;
        float4 v = (vv < nrows) ? *(const float4*)&X[(size_t)vv * DD + c4 * 4]
                                : make_float4(0.f, 0.f, 0.f, 0.f);
        union { __hip_bfloat162 h2[2]; short4v s; } u;
        u.h2[0] = __float22bfloat162_rn(make_float2(v.x, v.y));
        u.h2[1] = __float22bfloat162_rn(make_float2(v.z, v.w));
        *(short4v*)&Bs[row][c4 * 4] = u.s;
    }
    __syncthreads();

    f32x4 acc[4][4];
    #pragma unroll
    for (int mi = 0; mi < 4; ++mi)
        #pragma unroll
        for (int ni = 0; ni < 4; ++ni)
            acc[mi][ni] = (f32x4){0.f, 0.f, 0.f, 0.f};

    for (int ks = 0; ks < 4; ++ks) {
        const int kb = ks * 32 + lk * 8;
        bf16x8 ah[4], bh[4];
        #pragma unroll
        for (int mi = 0; mi < 4; ++mi) {
            int m = w * 64 + mi * 16 + lr;
            ah[mi] = *(const bf16x8*)&ABbf[m * DD + kb];
        }
        #pragma unroll
        for (int ni = 0; ni < 4; ++ni)
            bh[ni] = *(const bf16x8*)&Bs[ni * 16 + lr][kb];
        #pragma unroll
        for (int mi = 0; mi < 4; ++mi)
            #pragma unroll
            for (int ni = 0; ni < 4; ++ni)
                acc[mi][ni] = __builtin_amdgcn_mfma_f32_16x16x32_bf16(ah[mi], bh[ni], acc[mi][ni], 0, 0, 0);
    }

    #pragma unroll
    for (int ni = 0; ni < 4; ++ni) {
        int n = n0 + ni * 16 + lr;
        if (n >= nrows) continue;
        #pragma unroll
        for (int mi = 0; mi < 4; ++mi) {
            int m = w * 64 + mi * 16 + lk * 4;
            if (m < DD) store_acc(&OA[(size_t)n * DD + m], acc[mi][ni]);
            else        store_acc(&OB[(size_t)n * DD + (m - DD)], acc[mi][ni]);
        }
    }
}

// ---------------------------------------------------------------------------
// MFMA dual row-transform, bf16 input (for Hbf -> UH/VH).
// ---------------------------------------------------------------------------
template <typename OutT>
__global__ __launch_bounds__(256, 2) void k_mfma_dual(
    const short* __restrict__ Xbf, const short* __restrict__ ABbf,
    OutT* __restrict__ OA, OutT* __restrict__ OB, int nrows)
{
    const int n0 = blockIdx.x * 64;
    const int w  = threadIdx.x >> 6;
    const int l  = threadIdx.x & 63;
    const int lr = l & 15;
    const int lk = l >> 4;

    f32x4 acc[4][4];
    #pragma unroll
    for (int mi = 0; mi < 4; ++mi)
        #pragma unroll
        for (int ni = 0; ni < 4; ++ni)
            acc[mi][ni] = (f32x4){0.f, 0.f, 0.f, 0.f};

    const bf16x8 zf = {0, 0, 0, 0, 0, 0, 0, 0};

    for (int ks = 0; ks < 4; ++ks) {
        const int kb = ks * 32 + lk * 8;
        bf16x8 ah[4], bh[4];
        #pragma unroll
        for (int mi = 0; mi < 4; ++mi) {
            int m = w * 64 + mi * 16 + lr;
            ah[mi] = *(const bf16x8*)&ABbf[m * DD + kb];
        }
        #pragma unroll
        for (int ni = 0; ni < 4; ++ni) {
            int n = n0 + ni * 16 + lr;
            bh[ni] = (n < nrows) ? *(const bf16x8*)&Xbf[(size_t)n * DD + kb] : zf;
        }
        #pragma unroll
        for (int mi = 0; mi < 4; ++mi)
            #pragma unroll
            for (int ni = 0; ni < 4; ++ni)
                acc[mi][ni] = __builtin_amdgcn_mfma_f32_16x16x32_bf16(ah[mi], bh[ni], acc[mi][ni], 0, 0, 0);
    }

    #pragma unroll
    for (int ni = 0; ni < 4; ++ni) {
        int n = n0 + ni * 16 + lr;
        if (n >= nrows) continue;
        #pragma unroll
        for (int mi = 0; mi < 4; ++mi) {
            int m = w * 64 + mi * 16 + lk * 4;
            if (m < DD) store_acc(&OA[(size_t)n * DD + m], acc[mi][ni]);
            else        store_acc(&OB[(size_t)n * DD + (m - DD)], acc[mi][ni]);
        }
    }
}

// ---------------------------------------------------------------------------
// Kernel 2: per node n: r[d] = sum_k relu(WE[nid]+sum_e ME[gid]); h=softmax(r).
// R8 PINNED (43.9 us = FETCH 139 MB / 3.3 TB/s beyond-L2 ceiling; six
// variants R6-R12 all flat or worse) — do not touch.
// ---------------------------------------------------------------------------
__global__ __launch_bounds__(256, 7) void k_node(
    const int* __restrict__ node_ids, const int* __restrict__ neigh_ids,
    const __half* __restrict__ WE, const __half* __restrict__ ME,
    short* __restrict__ Hbf)
{
    __shared__ int idx[4][KK * (1 + DINT)];
    const int t  = threadIdx.x;
    const int n0 = blockIdx.x * 4;

    if (t < 4 * KK) idx[t >> 4][t & 15] = node_ids[n0 * KK + t];
    for (int x = t; x < 4 * KK * DINT; x += 256)
        idx[x >> 7][KK + (x & 127)] = neigh_ids[n0 * KK * DINT + x];
    __syncthreads();

    const int w   = t >> 6;
    const int l   = t & 63;
    const int g16 = l >> 4;
    const int p   = l & 15;
    const int n   = n0 + w;
    const int* ids = idx[w];

    float r[8] = {0.f, 0.f, 0.f, 0.f, 0.f, 0.f, 0.f, 0.f};
    #pragma unroll
    for (int kk = 0; kk < 4; ++kk) {
        const int k = kk * 4 + g16;
        half8 rw = *(const half8*)(WE + (size_t)ids[k] * DD + p * 8);
        half8 rm[DINT];
        #pragma unroll
        for (int e = 0; e < DINT; ++e)
            rm[e] = *(const half8*)(ME + (size_t)ids[KK + k * DINT + e] * DD + p * 8);

        float2 f0 = __half22float2(rw.a), f1 = __half22float2(rw.b);
        float2 f2 = __half22float2(rw.c), f3 = __half22float2(rw.d);
        float s[8] = {f0.x, f0.y, f1.x, f1.y, f2.x, f2.y, f3.x, f3.y};
        #pragma unroll
        for (int e = 0; e < DINT; ++e) {
            float2 m0 = __half22float2(rm[e].a), m1 = __half22float2(rm[e].b);
            float2 m2 = __half22float2(rm[e].c), m3 = __half22float2(rm[e].d);
            s[0] += m0.x; s[1] += m0.y; s[2] += m1.x; s[3] += m1.y;
            s[4] += m2.x; s[5] += m2.y; s[6] += m3.x; s[7] += m3.y;
        }
        #pragma unroll
        for (int j = 0; j < 8; ++j) r[j] += fmaxf(s[j], 0.f);
    }

    #pragma unroll
    for (int j = 0; j < 8; ++j) {
        r[j] += __shfl_xor(r[j], 16);
        r[j] += __shfl_xor(r[j], 32);
    }

    float mx = r[0];
    #pragma unroll
    for (int j = 1; j < 8; ++j) mx = fmaxf(mx, r[j]);
    #pragma unroll
    for (int off = 8; off >= 1; off >>= 1) mx = fmaxf(mx, __shfl_xor(mx, off));
    float e[8], sum = 0.f;
    #pragma unroll
    for (int j = 0; j < 8; ++j) { e[j] = expf(r[j] - mx); sum += e[j]; }
    #pragma unroll
    for (int off = 8; off >= 1; off >>= 1) sum += __shfl_xor(sum, off);
    float inv = 1.f / sum;
    if (g16 == 0) {
        bf16x8 o = {bf_rne(e[0] * inv), bf_rne(e[1] * inv), bf_rne(e[2] * inv), bf_rne(e[3] * inv),
                    bf_rne(e[4] * inv), bf_rne(e[5] * inv), bf_rne(e[6] * inv), bf_rne(e[7] * inv)};
        *(bf16x8*)(Hbf + (size_t)n * DD + p * 8) = o;
    }
}

// ---------------------------------------------------------------------------
// Kernel 3: e_all[n] = softmax(relu(UH[n] + sum_j VH[ext[n,j]])).
// Restructured to the k_node-proven shape: one node per wave-64, 4 groups
// of 16 lanes; lane (g,p) loads halfs [8p,8p+8) (16B half8); group g sums
// VH rows 4g..4g+3 (+UH on g==0). Combine via shfl_xor(16|32); softmax in
// the 16-lane group. Output EA written directly as bf16 (feeds k_mlp MFMA).
// ---------------------------------------------------------------------------
__global__ __launch_bounds__(256) void k_ext2(
    const int* __restrict__ ext_neigh, const __half* __restrict__ UH,
    const __half* __restrict__ VH, short* __restrict__ EAbf)
{
    __shared__ int idx[4][DEXT];
    const int t  = threadIdx.x;
    const int n0 = blockIdx.x * 4;
    if (t < 4 * DEXT) idx[t >> 4][t & 15] = ext_neigh[n0 * DEXT + t];
    __syncthreads();

    const int w = t >> 6;           // node within block
    const int l = t & 63;
    const int g = l >> 4;           // row-group 0..3
    const int p = l & 15;           // 16B-chunk position
    const int n = n0 + w;
    const int po = p * 8;

    float s[8] = {0.f, 0.f, 0.f, 0.f, 0.f, 0.f, 0.f, 0.f};
    if (g == 0) {
        half8 a = *(const half8*)(UH + (size_t)n * DD + po);
        float2 a0 = __half22float2(a.a), a1 = __half22float2(a.b);
        float2 a2 = __half22float2(a.c), a3 = __half22float2(a.d);
        s[0] = a0.x; s[1] = a0.y; s[2] = a1.x; s[3] = a1.y;
        s[4] = a2.x; s[5] = a2.y; s[6] = a3.x; s[7] = a3.y;
    }
    #pragma unroll
    for (int jj = 0; jj < 4; ++jj) {
        half8 v = *(const half8*)(VH + (size_t)idx[w][g * 4 + jj] * DD + po);
        float2 v0 = __half22float2(v.a), v1 = __half22float2(v.b);
        float2 v2 = __half22float2(v.c), v3 = __half22float2(v.d);
        s[0] += v0.x; s[1] += v0.y; s[2] += v1.x; s[3] += v1.y;
        s[4] += v2.x; s[5] += v2.y; s[6] += v3.x; s[7] += v3.y;
    }

    #pragma unroll
    for (int j = 0; j < 8; ++j) {
        s[j] += __shfl_xor(s[j], 16);
        s[j] += __shfl_xor(s[j], 32);
        s[j] = fmaxf(s[j], 0.f);
    }

    float mx = s[0];
    #pragma unroll
    for (int j = 1; j < 8; ++j) mx = fmaxf(mx, s[j]);
    #pragma unroll
    for (int off = 8; off >= 1; off >>= 1) mx = fmaxf(mx, __shfl_xor(mx, off));
    float e[8], sum = 0.f;
    #pragma unroll
    for (int j = 0; j < 8; ++j) { e[j] = expf(s[j] - mx); sum += e[j]; }
    #pragma unroll
    for (int off = 8; off >= 1; off >>= 1) sum += __shfl_xor(sum, off);
    float inv = 1.f / sum;
    if (g == 0) {
        bf16x8 o = {bf_rne(e[0] * inv), bf_rne(e[1] * inv), bf_rne(e[2] * inv), bf_rne(e[3] * inv),
                    bf_rne(e[4] * inv), bf_rne(e[5] * inv), bf_rne(e[6] * inv), bf_rne(e[7] * inv)};
        *(bf16x8*)(EAbf + (size_t)n * DD + po) = o;
    }
}

// ---------------------------------------------------------------------------
// Kernel 4 (MFMA): 32 batch pairs per block (grid 64 for 2x CU coverage).
// X = leaky(W1 @ cat^T + b1); logits = W2 @ X + b2; softmax-2.
// EA is bf16 -> fragments load directly, no cvt.
// ---------------------------------------------------------------------------
__global__ __launch_bounds__(256) void k_mlp_mfma(
    const int* __restrict__ batch, const short* __restrict__ EAbf,
    const short* __restrict__ W1bf, const float* __restrict__ b1,
    const float* __restrict__ W2, const float* __restrict__ b2,
    float* __restrict__ out)
{
    __shared__ int pidx[64];
    __shared__ float red0[4][32];
    __shared__ float red1[4][32];
    const int t = threadIdx.x, w = t >> 6, l = t & 63;
    const int lr = l & 15, lk = l >> 4;
    const int b0 = blockIdx.x * 32;

    if (t < 64) pidx[t] = batch[b0 * 2 + t];
    __syncthreads();

    f32x4 acc[2][2];
    #pragma unroll
    for (int mi = 0; mi < 2; ++mi)
        #pragma unroll
        for (int ni = 0; ni < 2; ++ni)
            acc[mi][ni] = (f32x4){0.f, 0.f, 0.f, 0.f};

    for (int ks = 0; ks < 8; ++ks) {
        const int kb = ks * 32 + lk * 8;
        const int sel = (ks >= 4);
        const int koff = kb - sel * 128;
        bf16x8 ah[2], bh[2];
        #pragma unroll
        for (int mi = 0; mi < 2; ++mi) {
            int m = w * 32 + mi * 16 + lr;
            ah[mi] = *(const bf16x8*)&W1bf[m * (2 * DD) + kb];
        }
        #pragma unroll
        for (int ni = 0; ni < 2; ++ni) {
            int n = ni * 16 + lr;
            int row = pidx[2 * n + sel];
            bh[ni] = *(const bf16x8*)&EAbf[(size_t)row * DD + koff];
        }
        #pragma unroll
        for (int mi = 0; mi < 2; ++mi)
            #pragma unroll
            for (int ni = 0; ni < 2; ++ni)
                acc[mi][ni] = __builtin_amdgcn_mfma_f32_16x16x32_bf16(ah[mi], bh[ni], acc[mi][ni], 0, 0, 0);
    }

    float bb[2][4], w2a[2][4], w2b[2][4];
    #pragma unroll
    for (int mi = 0; mi < 2; ++mi)
        #pragma unroll
        for (int rr = 0; rr < 4; ++rr) {
            int m = w * 32 + mi * 16 + lk * 4 + rr;
            bb[mi][rr]  = b1[m];
            w2a[mi][rr] = W2[m];
            w2b[mi][rr] = W2[DD + m];
        }

    #pragma unroll
    for (int ni = 0; ni < 2; ++ni) {
        float p0 = 0.f, p1 = 0.f;
        #pragma unroll
        for (int mi = 0; mi < 2; ++mi)
            #pragma unroll
            for (int rr = 0; rr < 4; ++rr) {
                float x = acc[mi][ni][rr] + bb[mi][rr];
                x = (x > 0.f) ? x : 0.01f * x;
                p0 = fmaf(w2a[mi][rr], x, p0);
                p1 = fmaf(w2b[mi][rr], x, p1);
            }
        p0 += __shfl_xor(p0, 16); p0 += __shfl_xor(p0, 32);
        p1 += __shfl_xor(p1, 16); p1 += __shfl_xor(p1, 32);
        if (lk == 0) {
            red0[w][ni * 16 + lr] = p0;
            red1[w][ni * 16 + lr] = p1;
        }
    }
    __syncthreads();
    if (t < 32) {
        float l0 = red0[0][t] + red0[1][t] + red0[2][t] + red0[3][t] + b2[0];
        float l1 = red1[0][t] + red1[1][t] + red1[2][t] + red1[3][t] + b2[1];
        float mm = fmaxf(l0, l1);
        float e0 = expf(l0 - mm), e1 = expf(l1 - mm);
        float inv = 1.f / (e0 + e1);
        out[2 * (b0 + t)]     = e0 * inv;
        out[2 * (b0 + t) + 1] = e1 * inv;
    }
}

// ---------------------------------------------------------------------------
extern "C" void kernel_launch(void* const* d_in, const int* in_sizes, int n_in,
                              void* d_out, int out_size, void* d_ws, size_t ws_size,
                              hipStream_t stream) {
    const int*   batch     = (const int*)d_in[0];
    const int*   node_ids  = (const int*)d_in[1];
    const int*   neigh_ids = (const int*)d_in[2];
    const int*   ext_neigh = (const int*)d_in[3];
    const float* E         = (const float*)d_in[4];
    const float* W         = (const float*)d_in[5];
    const float* M         = (const float*)d_in[6];
    const float* U         = (const float*)d_in[7];
    const float* V         = (const float*)d_in[8];
    const float* W1        = (const float*)d_in[9];
    const float* b1        = (const float*)d_in[10];
    const float* W2        = (const float*)d_in[11];
    const float* b2        = (const float*)d_in[12];

    // workspace layout (~36.6 MB, all 16B-aligned)
    __half* WE   = (__half*)d_ws;                    // 12.8 MB
    __half* ME   = WE + (size_t)VINT * DD;           // 12.8 MB
    short*  Hbf  = (short*)(ME + (size_t)VINT * DD); // 2.56 MB
    short*  WMbf = Hbf + (size_t)NN * DD;            // 64 KB
    short*  UVbf = WMbf + 256 * DD;                  // 64 KB
    short*  W1bf = UVbf + 256 * DD;                  // 64 KB
    __half* UHh  = (__half*)(W1bf + DD * 2 * DD);    // 2.56 MB
    __half* VHh  = UHh + (size_t)NN * DD;            // 2.56 MB
    short*  EAbf = (short*)(VHh + (size_t)NN * DD);  // 2.56 MB
    float*  out  = (float*)d_out;

    k_convert_mats<<<96, 256, 0, stream>>>(W, M, U, V, W1, WMbf, UVbf, W1bf);
    k_mfma_dual_f32lds<__half><<<(VINT + 63) / 64, 256, 0, stream>>>(E, WMbf, WE, ME, VINT);
    k_node<<<NN / 4, 256, 0, stream>>>(node_ids, neigh_ids, WE, ME, Hbf);
    k_mfma_dual<__half><<<(NN + 63) / 64, 256, 0, stream>>>(Hbf, UVbf, UHh, VHh, NN);
    k_ext2<<<NN / 4, 256, 0, stream>>>(ext_neigh, UHh, VHh, EAbf);
    k_mlp_mfma<<<BB / 32, 256, 0, stream>>>(batch, EAbf, W1bf, b1, W2, b2, out);
}